// Round 3
// baseline (1688.190 us; speedup 1.0000x reference)
//
#include <hip/hip_runtime.h>

#define BS 16
#define CI 2048
#define NI 16
#define CO 64
#define NO 32
#define KK 2048   // CO*NO
#define GBLK 256  // blocks; each handles 8 capsules i (i = blk + il*GBLK)

__device__ __forceinline__ void load_lds16(const float* g, float* l) {
    __builtin_amdgcn_global_load_lds(
        (const __attribute__((address_space(1))) void*)g,
        (__attribute__((address_space(3))) void*)l,
        16, 0, 0);
}

// MODE 0: iter1 (uniform route) -> raw vote sums
// MODE 1: iter2 (logits = dist; store logits at end)
// MODE 2: iter3 (logits = stored + dist)
template <int MODE>
__global__ __launch_bounds__(512) void pass_kernel(
    const float* __restrict__ x,      // [BS][CI][NI]
    const float* __restrict__ w,      // [CI][NI][KK]
    const float* __restrict__ act_in, // [BS][KK]
    float* __restrict__ logits,       // [BS][CI][CO]
    float* __restrict__ partials)     // [GBLK][BS][KK]
{
    __shared__ float wbuf[2][8][KK];  // 128 KB, double-buffered half-i tiles
    __shared__ float xb[8][BS][NI];   // 8 KB: x for this block's 8 capsules
    __shared__ float sm[BS * 65];     // softmax exchange, padded stride

    const int t = threadIdx.x;        // 0..511
    const int blk = blockIdx.x;
    const int k0 = 4 * t;             // this thread's quad of k
    const int co = t >> 3;
    const int b0 = t >> 6;            // softmax row pair (b0, b0+8)
    const int cs = t & 63;

    // ---- stage x for all 8 i's (one float4 per thread) ----
    {
        int il = t >> 6;
        int b = (t >> 2) & 15;
        int n0 = (t & 3) * 4;
        int i = blk + il * GBLK;
        float4 xv = *(const float4*)&x[((size_t)b * CI + i) * NI + n0];
        *(float4*)&xb[il][b][n0] = xv;
    }

    // ---- logits in registers: keeps the vmcnt stream pure ----
    float lgA[8], lgB[8];
    if constexpr (MODE == 2) {
#pragma unroll
        for (int il = 0; il < 8; ++il) {
            int i = blk + il * GBLK;
            lgA[il] = logits[((size_t)b0 * CI + i) * CO + cs];
            lgB[il] = logits[((size_t)(b0 + 8) * CI + i) * CO + cs];
        }
    }
    __syncthreads();  // drains vmcnt/lgkmcnt once; x visible to all

    float4 acc[BS];
#pragma unroll
    for (int b = 0; b < BS; ++b) acc[b] = make_float4(0.f, 0.f, 0.f, 0.f);

    // issue one half-tile (8 ni rows) of weights direct to LDS: 8 instrs/thread,
    // zero VGPR in-flight cost. Thread t's slots are written & read only by t.
    auto issue = [&](int h) {
        int il = h >> 1, p = h & 1;
        const float* gb = w + (((size_t)(blk + il * GBLK) * NI + p * 8) * KK) + k0;
        float* lb = &wbuf[p][0][k0];
#pragma unroll
        for (int r = 0; r < 8; ++r)
            load_lds16(gb + (size_t)r * KK, lb + (size_t)r * KK);
    };

    issue(0);
    issue(1);

    for (int il = 0; il < 8; ++il) {
        float4 v[BS];
        if constexpr (MODE != 0) {
#pragma unroll
            for (int b = 0; b < BS; ++b) v[b] = make_float4(0.f, 0.f, 0.f, 0.f);
        }

        auto compute_half = [&](int p, float4(&dst)[BS]) {
#pragma unroll
            for (int rg = 0; rg < 2; ++rg) {
                float4 w0 = *(const float4*)&wbuf[p][rg * 4 + 0][k0];
                float4 w1 = *(const float4*)&wbuf[p][rg * 4 + 1][k0];
                float4 w2 = *(const float4*)&wbuf[p][rg * 4 + 2][k0];
                float4 w3 = *(const float4*)&wbuf[p][rg * 4 + 3][k0];
#pragma unroll
                for (int b = 0; b < BS; ++b) {
                    float4 xv = *(const float4*)&xb[il][b][p * 8 + rg * 4];
                    dst[b].x = fmaf(xv.x, w0.x, dst[b].x);
                    dst[b].y = fmaf(xv.x, w0.y, dst[b].y);
                    dst[b].z = fmaf(xv.x, w0.z, dst[b].z);
                    dst[b].w = fmaf(xv.x, w0.w, dst[b].w);
                    dst[b].x = fmaf(xv.y, w1.x, dst[b].x);
                    dst[b].y = fmaf(xv.y, w1.y, dst[b].y);
                    dst[b].z = fmaf(xv.y, w1.z, dst[b].z);
                    dst[b].w = fmaf(xv.y, w1.w, dst[b].w);
                    dst[b].x = fmaf(xv.z, w2.x, dst[b].x);
                    dst[b].y = fmaf(xv.z, w2.y, dst[b].y);
                    dst[b].z = fmaf(xv.z, w2.z, dst[b].z);
                    dst[b].w = fmaf(xv.z, w2.w, dst[b].w);
                    dst[b].x = fmaf(xv.w, w3.x, dst[b].x);
                    dst[b].y = fmaf(xv.w, w3.y, dst[b].y);
                    dst[b].z = fmaf(xv.w, w3.z, dst[b].z);
                    dst[b].w = fmaf(xv.w, w3.w, dst[b].w);
                }
            }
        };

        // ---- half 0: rows 0..7 of capsule il ----
        asm volatile("s_waitcnt vmcnt(8)" ::: "memory");  // batch 2il done, 2il+1 in flight
        if constexpr (MODE == 0) compute_half(0, acc); else compute_half(0, v);
        asm volatile("s_waitcnt lgkmcnt(0)" ::: "memory");  // buffer reads retired
        if (il < 7) issue(2 * il + 2);

        // ---- half 1: rows 8..15 ----
        if (il < 7) asm volatile("s_waitcnt vmcnt(8)" ::: "memory");
        else        asm volatile("s_waitcnt vmcnt(0)" ::: "memory");
        if constexpr (MODE == 0) compute_half(1, acc); else compute_half(1, v);
        asm volatile("s_waitcnt lgkmcnt(0)" ::: "memory");

        if constexpr (MODE == 0) {
            if (il < 7) issue(2 * il + 3);
        } else {
            // act loads BEFORE next prefetch batch so counted vmcnt drains them
            float4 a4[BS];
#pragma unroll
            for (int b = 0; b < BS; ++b)
                a4[b] = *(const float4*)&act_in[(size_t)b * KK + k0];
            asm volatile("" ::: "memory");  // pin order: acts precede prefetch
            if (il < 7) {
                issue(2 * il + 3);
                asm volatile("s_waitcnt vmcnt(8)" ::: "memory");  // drains acts+2il+2, keeps 2il+3
            } else {
                asm volatile("s_waitcnt vmcnt(0)" ::: "memory");
            }

            // distances dp[b] = sum_{no quad} v*act, then 8-lane reduce per co
            float dp[BS];
#pragma unroll
            for (int b = 0; b < BS; ++b)
                dp[b] = v[b].x * a4[b].x + v[b].y * a4[b].y +
                        v[b].z * a4[b].z + v[b].w * a4[b].w;
#pragma unroll
            for (int b = 0; b < BS; ++b) {
#pragma unroll
                for (int m = 1; m < 8; m <<= 1)
                    dp[b] += __shfl_xor(dp[b], m, 8);
            }
            {
                int j = t & 7;
                sm[j * 65 + co] = dp[j];
                sm[(j + 8) * 65 + co] = dp[j + 8];
            }
            // raw barrier: LDS writes drained, weight prefetch stays in flight
            asm volatile("s_waitcnt lgkmcnt(0)" ::: "memory");
            __builtin_amdgcn_s_barrier();

            {   // softmax over co: thread handles (b0,cs) and (b0+8,cs)
                float d0 = sm[b0 * 65 + cs];
                float d1 = sm[(b0 + 8) * 65 + cs];
                float l0, l1;
                if constexpr (MODE == 1) {
                    l0 = d0; l1 = d1;
                    lgA[il] = d0; lgB[il] = d1;  // store to global at end
                } else {
                    l0 = lgA[il] + d0;
                    l1 = lgB[il] + d1;
                }
                float m0 = l0, m1 = l1;
#pragma unroll
                for (int m = 1; m < 64; m <<= 1) {
                    m0 = fmaxf(m0, __shfl_xor(m0, m, 64));
                    m1 = fmaxf(m1, __shfl_xor(m1, m, 64));
                }
                float e0 = __expf(l0 - m0), e1 = __expf(l1 - m1);
                float s0 = e0, s1 = e1;
#pragma unroll
                for (int m = 1; m < 64; m <<= 1) {
                    s0 += __shfl_xor(s0, m, 64);
                    s1 += __shfl_xor(s1, m, 64);
                }
                sm[b0 * 65 + cs] = e0 / s0;
                sm[(b0 + 8) * 65 + cs] = e1 / s1;
            }
            asm volatile("s_waitcnt lgkmcnt(0)" ::: "memory");
            __builtin_amdgcn_s_barrier();

            // routed accumulate
#pragma unroll
            for (int b = 0; b < BS; ++b) {
                float r = sm[b * 65 + co];
                acc[b].x = fmaf(r, v[b].x, acc[b].x);
                acc[b].y = fmaf(r, v[b].y, acc[b].y);
                acc[b].z = fmaf(r, v[b].z, acc[b].z);
                acc[b].w = fmaf(r, v[b].w, acc[b].w);
            }
            asm volatile("s_waitcnt lgkmcnt(0)" ::: "memory");
            __builtin_amdgcn_s_barrier();  // sm reads done before next i's writes
        }
    }

    // ---- epilogue: stores only after the pipeline is drained ----
#pragma unroll
    for (int b = 0; b < BS; ++b)
        *(float4*)&partials[((size_t)blk * BS + b) * KK + k0] = acc[b];

    if constexpr (MODE == 1) {
#pragma unroll
        for (int il = 0; il < 8; ++il) {
            int i = blk + il * GBLK;
            logits[((size_t)b0 * CI + i) * CO + cs] = lgA[il];
            logits[((size_t)(b0 + 8) * CI + i) * CO + cs] = lgB[il];
        }
    }
}

__global__ __launch_bounds__(256) void reduce_squash(
    const float* __restrict__ partials,
    const float* __restrict__ bias,
    float* __restrict__ act_out, float scale)
{
    int tid = blockIdx.x * 256 + threadIdx.x;  // 0..32767
    int b = tid >> 11;
    int k = tid & (KK - 1);
    const float* p = partials + (size_t)b * KK + k;
    const size_t stride = (size_t)BS * KK;
    float s0 = 0.f, s1 = 0.f, s2 = 0.f, s3 = 0.f;
    for (int g = 0; g < GBLK; g += 4) {
        s0 += p[(size_t)g * stride];
        s1 += p[(size_t)(g + 1) * stride];
        s2 += p[(size_t)(g + 2) * stride];
        s3 += p[(size_t)(g + 3) * stride];
    }
    float v = (s0 + s1) + (s2 + s3);
    v = v * scale + bias[k];
    float n2 = v * v;
#pragma unroll
    for (int m = 1; m < 32; m <<= 1) n2 += __shfl_xor(n2, m, 32);
    float norm = sqrtf(n2);
    act_out[tid] = v * norm / (1.f + n2);
}

extern "C" void kernel_launch(void* const* d_in, const int* in_sizes, int n_in,
                              void* d_out, int out_size, void* d_ws, size_t ws_size,
                              hipStream_t stream) {
    const float* x = (const float*)d_in[0];
    const float* w = (const float*)d_in[1];
    const float* bias = (const float*)d_in[2];
    float* out = (float*)d_out;

    char* p = (char*)d_ws;
    float* partials = (float*)p; p += (size_t)GBLK * BS * KK * 4;  // 33.5 MB
    float* logits = (float*)p;   p += (size_t)BS * CI * CO * 4;    // 8 MB
    float* act1 = (float*)p;     p += (size_t)BS * KK * 4;
    float* act2 = (float*)p;

    dim3 blk(512), grid(GBLK);
    pass_kernel<0><<<grid, blk, 0, stream>>>(x, w, nullptr, logits, partials);
    reduce_squash<<<128, 256, 0, stream>>>(partials, bias, act1, 1.0f / (float)CO);
    pass_kernel<1><<<grid, blk, 0, stream>>>(x, w, act1, logits, partials);
    reduce_squash<<<128, 256, 0, stream>>>(partials, bias, act2, 1.0f);
    pass_kernel<2><<<grid, blk, 0, stream>>>(x, w, act2, logits, partials);
    reduce_squash<<<128, 256, 0, stream>>>(partials, bias, out, 1.0f);
}

// Round 4
// 566.635 us; speedup vs baseline: 2.9793x; 2.9793x over previous
//
#include <hip/hip_runtime.h>

#define BS 16
#define CI 2048
#define NI 16
#define CO 64
#define NO 32
#define KK 2048   // CO*NO
#define GBLK 256  // blocks; each handles 8 capsules i (i = blk + il*GBLK)

__device__ __forceinline__ void load_lds16(const float* g, float* l) {
    __builtin_amdgcn_global_load_lds(
        (const __attribute__((address_space(1))) void*)g,
        (__attribute__((address_space(3))) void*)l,
        16, 0, 0);
}

// MODE 0: iter1 (uniform route) -> raw vote sums
// MODE 1: iter2 (logits = dist; store logits at end)
// MODE 2: iter3 (logits = stored + dist)
template <int MODE>
__global__ __launch_bounds__(512, 2) void pass_kernel(
    const float* __restrict__ x,      // [BS][CI][NI]
    const float* __restrict__ w,      // [CI][NI][KK]
    const float* __restrict__ act_in, // [BS][KK]
    float* __restrict__ logits,       // [BS][CI][CO]
    float* __restrict__ partials)     // [GBLK][BS][KK]
{
    __shared__ float wbuf[2][8][KK];  // 128 KB, double-buffered half-i tiles
    __shared__ float xb[8][BS][NI];   // 8 KB
    __shared__ float sm[BS * 65];     // softmax exchange, padded

    const int t = threadIdx.x;        // 0..511
    const int blk = blockIdx.x;
    const int k0 = 4 * t;
    const int co = t >> 3;
    const int b0 = t >> 6;
    const int cs = t & 63;

    // ---- pre-loop: x -> LDS, act -> regs (il-invariant!), logits -> regs ----
    {
        int il = t >> 6, b = (t >> 2) & 15, n0 = (t & 3) * 4;
        int i = blk + il * GBLK;
        *(float4*)&xb[il][b][n0] = *(const float4*)&x[((size_t)b * CI + i) * NI + n0];
    }
    float4 a4[BS];
    if constexpr (MODE != 0) {
#pragma unroll
        for (int b = 0; b < BS; ++b)
            a4[b] = *(const float4*)&act_in[(size_t)b * KK + k0];
    }
    float lgA[8], lgB[8];
    if constexpr (MODE == 2) {
#pragma unroll
        for (int il = 0; il < 8; ++il) {
            int i = blk + il * GBLK;
            lgA[il] = logits[((size_t)b0 * CI + i) * CO + cs];
            lgB[il] = logits[((size_t)(b0 + 8) * CI + i) * CO + cs];
        }
    }
    __syncthreads();  // drains all counters; clean slate for the pipeline

    float4 acc[BS];
#pragma unroll
    for (int b = 0; b < BS; ++b) acc[b] = make_float4(0.f, 0.f, 0.f, 0.f);

    // one half-tile (8 ni rows) of weights direct to LDS; thread t's slots are
    // written and read only by thread t (lane-linear dest), so no barriers.
    auto issue = [&](int h) {
        int il = h >> 1, p = h & 1;
        const float* gb = w + (((size_t)(blk + il * GBLK) * NI + p * 8) * KK) + k0;
        float* lb = &wbuf[p][0][k0];
#pragma unroll
        for (int r = 0; r < 8; ++r)
            load_lds16(gb + (size_t)r * KK, lb + (size_t)r * KK);
    };

    auto compute_half = [&](int il, int p, float4(&dst)[BS]) {
#pragma unroll
        for (int rg = 0; rg < 2; ++rg) {
            float4 w0 = *(const float4*)&wbuf[p][rg * 4 + 0][k0];
            float4 w1 = *(const float4*)&wbuf[p][rg * 4 + 1][k0];
            float4 w2 = *(const float4*)&wbuf[p][rg * 4 + 2][k0];
            float4 w3 = *(const float4*)&wbuf[p][rg * 4 + 3][k0];
#pragma unroll
            for (int b = 0; b < BS; ++b) {
                float4 xv = *(const float4*)&xb[il][b][p * 8 + rg * 4];
                dst[b].x = fmaf(xv.x, w0.x, dst[b].x);
                dst[b].y = fmaf(xv.x, w0.y, dst[b].y);
                dst[b].z = fmaf(xv.x, w0.z, dst[b].z);
                dst[b].w = fmaf(xv.x, w0.w, dst[b].w);
                dst[b].x = fmaf(xv.y, w1.x, dst[b].x);
                dst[b].y = fmaf(xv.y, w1.y, dst[b].y);
                dst[b].z = fmaf(xv.y, w1.z, dst[b].z);
                dst[b].w = fmaf(xv.y, w1.w, dst[b].w);
                dst[b].x = fmaf(xv.z, w2.x, dst[b].x);
                dst[b].y = fmaf(xv.z, w2.y, dst[b].y);
                dst[b].z = fmaf(xv.z, w2.z, dst[b].z);
                dst[b].w = fmaf(xv.z, w2.w, dst[b].w);
                dst[b].x = fmaf(xv.w, w3.x, dst[b].x);
                dst[b].y = fmaf(xv.w, w3.y, dst[b].y);
                dst[b].z = fmaf(xv.w, w3.z, dst[b].z);
                dst[b].w = fmaf(xv.w, w3.w, dst[b].w);
            }
        }
    };

    issue(0);
    issue(1);

#pragma unroll
    for (int il = 0; il < 8; ++il) {
        float4 v[BS];
        if constexpr (MODE != 0) {
#pragma unroll
            for (int b = 0; b < BS; ++b) v[b] = make_float4(0.f, 0.f, 0.f, 0.f);
        }

        // half 0
        asm volatile("s_waitcnt vmcnt(8)" ::: "memory");
        if constexpr (MODE == 0) compute_half(il, 0, acc); else compute_half(il, 0, v);
        asm volatile("s_waitcnt lgkmcnt(0)" ::: "memory");
        if (il < 7) issue(2 * il + 2);

        // half 1
        if (il < 7) asm volatile("s_waitcnt vmcnt(8)" ::: "memory");
        else        asm volatile("s_waitcnt vmcnt(0)" ::: "memory");
        if constexpr (MODE == 0) compute_half(il, 1, acc); else compute_half(il, 1, v);
        asm volatile("s_waitcnt lgkmcnt(0)" ::: "memory");
        if (il < 7) issue(2 * il + 3);

        if constexpr (MODE != 0) {
            // distances from pinned act regs (no loads in this phase)
            float dp[BS];
#pragma unroll
            for (int b = 0; b < BS; ++b)
                dp[b] = v[b].x * a4[b].x + v[b].y * a4[b].y +
                        v[b].z * a4[b].z + v[b].w * a4[b].w;
#pragma unroll
            for (int b = 0; b < BS; ++b) {
#pragma unroll
                for (int m = 1; m < 8; m <<= 1)
                    dp[b] += __shfl_xor(dp[b], m, 8);
            }
            {
                int j = t & 7;
                sm[j * 65 + co] = dp[j];
                sm[(j + 8) * 65 + co] = dp[j + 8];
            }
            asm volatile("s_waitcnt lgkmcnt(0)" ::: "memory");
            __builtin_amdgcn_s_barrier();   // raw: weight prefetch stays in flight

            {   // softmax over co
                float d0 = sm[b0 * 65 + cs];
                float d1 = sm[(b0 + 8) * 65 + cs];
                float l0, l1;
                if constexpr (MODE == 1) {
                    l0 = d0; l1 = d1;
                    lgA[il] = d0; lgB[il] = d1;
                } else {
                    l0 = lgA[il] + d0;
                    l1 = lgB[il] + d1;
                }
                float m0 = l0, m1 = l1;
#pragma unroll
                for (int m = 1; m < 64; m <<= 1) {
                    m0 = fmaxf(m0, __shfl_xor(m0, m, 64));
                    m1 = fmaxf(m1, __shfl_xor(m1, m, 64));
                }
                float e0 = __expf(l0 - m0), e1 = __expf(l1 - m1);
                float s0 = e0, s1 = e1;
#pragma unroll
                for (int m = 1; m < 64; m <<= 1) {
                    s0 += __shfl_xor(s0, m, 64);
                    s1 += __shfl_xor(s1, m, 64);
                }
                sm[b0 * 65 + cs] = e0 / s0;
                sm[(b0 + 8) * 65 + cs] = e1 / s1;
            }
            asm volatile("s_waitcnt lgkmcnt(0)" ::: "memory");
            __builtin_amdgcn_s_barrier();

            // routed accumulate
#pragma unroll
            for (int b = 0; b < BS; ++b) {
                float r = sm[b * 65 + co];
                acc[b].x = fmaf(r, v[b].x, acc[b].x);
                acc[b].y = fmaf(r, v[b].y, acc[b].y);
                acc[b].z = fmaf(r, v[b].z, acc[b].z);
                acc[b].w = fmaf(r, v[b].w, acc[b].w);
            }
            asm volatile("s_waitcnt lgkmcnt(0)" ::: "memory");
            __builtin_amdgcn_s_barrier();   // sm reads done before next il writes
        }
    }

    // epilogue (pipeline fully drained by il=7's vmcnt(0))
#pragma unroll
    for (int b = 0; b < BS; ++b)
        *(float4*)&partials[((size_t)blk * BS + b) * KK + k0] = acc[b];

    if constexpr (MODE == 1) {
#pragma unroll
        for (int il = 0; il < 8; ++il) {
            int i = blk + il * GBLK;
            logits[((size_t)b0 * CI + i) * CO + cs] = lgA[il];
            logits[((size_t)(b0 + 8) * CI + i) * CO + cs] = lgB[il];
        }
    }
}

// 256 blocks x 128 threads; block owns 128 outputs; 4-way split over G + LDS combine
__global__ __launch_bounds__(128) void reduce_squash(
    const float* __restrict__ partials,
    const float* __restrict__ bias,
    float* __restrict__ act_out, float scale)
{
    __shared__ float4 sred[4][32];
    const int t = threadIdx.x;       // 0..127
    const int blk = blockIdx.x;      // 0..255
    const int lane = t & 31;
    const int gp = t >> 5;           // 0..3
    const int o4 = blk * 128 + lane * 4;
    const int b = o4 >> 11;
    const int kk = o4 & (KK - 1);
    const float* p = partials + (size_t)b * KK + kk;
    const size_t stride = (size_t)BS * KK;

    float4 s = make_float4(0.f, 0.f, 0.f, 0.f);
#pragma unroll 4
    for (int g = gp * 64; g < gp * 64 + 64; ++g) {
        float4 v = *(const float4*)(p + (size_t)g * stride);
        s.x += v.x; s.y += v.y; s.z += v.z; s.w += v.w;
    }
    sred[gp][lane] = s;
    __syncthreads();

    if (t < 32) {
        float4 v0 = sred[0][t], v1 = sred[1][t], v2 = sred[2][t], v3 = sred[3][t];
        float4 v;
        v.x = (v0.x + v1.x) + (v2.x + v3.x);
        v.y = (v0.y + v1.y) + (v2.y + v3.y);
        v.z = (v0.z + v1.z) + (v2.z + v3.z);
        v.w = (v0.w + v1.w) + (v2.w + v3.w);
        const int ot = blk * 128 + t * 4;
        float4 bb = *(const float4*)&bias[ot & (KK - 1)];
        v.x = v.x * scale + bb.x;
        v.y = v.y * scale + bb.y;
        v.z = v.z * scale + bb.z;
        v.w = v.w * scale + bb.w;
        // squash over 32-no group = 8 lanes x 4 elems
        float n2 = v.x * v.x + v.y * v.y + v.z * v.z + v.w * v.w;
#pragma unroll
        for (int m = 1; m < 8; m <<= 1) n2 += __shfl_xor(n2, m, 8);
        float norm = sqrtf(n2);
        float sc = norm / (1.f + n2);
        float4 o = make_float4(v.x * sc, v.y * sc, v.z * sc, v.w * sc);
        *(float4*)&act_out[ot] = o;
    }
}

extern "C" void kernel_launch(void* const* d_in, const int* in_sizes, int n_in,
                              void* d_out, int out_size, void* d_ws, size_t ws_size,
                              hipStream_t stream) {
    const float* x = (const float*)d_in[0];
    const float* w = (const float*)d_in[1];
    const float* bias = (const float*)d_in[2];
    float* out = (float*)d_out;

    char* p = (char*)d_ws;
    float* partials = (float*)p; p += (size_t)GBLK * BS * KK * 4;  // 33.5 MB
    float* logits = (float*)p;   p += (size_t)BS * CI * CO * 4;    // 8 MB
    float* act1 = (float*)p;     p += (size_t)BS * KK * 4;
    float* act2 = (float*)p;

    dim3 blk(512), grid(GBLK);
    pass_kernel<0><<<grid, blk, 0, stream>>>(x, w, nullptr, logits, partials);
    reduce_squash<<<256, 128, 0, stream>>>(partials, bias, act1, 1.0f / (float)CO);
    pass_kernel<1><<<grid, blk, 0, stream>>>(x, w, act1, logits, partials);
    reduce_squash<<<256, 128, 0, stream>>>(partials, bias, act2, 1.0f);
    pass_kernel<2><<<grid, blk, 0, stream>>>(x, w, act2, logits, partials);
    reduce_squash<<<256, 128, 0, stream>>>(partials, bias, out, 1.0f);
}

// Round 5
// 546.818 us; speedup vs baseline: 3.0873x; 1.0362x over previous
//
#include <hip/hip_runtime.h>

#define BS 16
#define CI 2048
#define NI 16
#define CO 64
#define NO 32
#define KK 2048   // CO*NO
#define GBLK 256  // blocks; each handles 8 capsules i (i = blk + il*GBLK)

__device__ __forceinline__ void load_lds16(const float* g, float* l) {
    __builtin_amdgcn_global_load_lds(
        (const __attribute__((address_space(1))) void*)g,
        (__attribute__((address_space(3))) void*)l,
        16, 0, 0);
}

#define WAITVM4 asm volatile("s_waitcnt vmcnt(4)" ::: "memory")
#define WAITVM0 asm volatile("s_waitcnt vmcnt(0)" ::: "memory")
#define WAITLGKM asm volatile("s_waitcnt lgkmcnt(0)" ::: "memory")
#define BAR __builtin_amdgcn_s_barrier

// 1024 threads: batch-half h = t>>9 (b 0-7 or 8-15), u = t&511 owns k quad 4u.
// MODE 0: iter1 (uniform route); MODE 1: iter2 (store logits); MODE 2: iter3.
template <int MODE>
__global__ __launch_bounds__(1024, 4) void pass_kernel(
    const float* __restrict__ x,      // [BS][CI][NI]
    const float* __restrict__ w,      // [CI][NI][KK]
    const float* __restrict__ act_in, // [BS][KK]
    float* __restrict__ logits,       // [BS][CI][CO]
    float* __restrict__ partials)     // [GBLK][BS][KK]
{
    __shared__ float wbuf[2][8 * KK]; // 128 KB, double-buffered ni-half tiles
    __shared__ float xb[8][BS][NI];   // 8 KB
    __shared__ float sm[BS * 65];     // softmax exchange, padded

    const int t = threadIdx.x;        // 0..1023
    const int blk = blockIdx.x;
    const int h = t >> 9;             // batch half: 0 -> b 0-7, 1 -> b 8-15
    const int u = t & 511;
    const int k4 = 4 * u;             // this thread's k quad
    const int co = u >> 3;            // k4 / 32
    const int j8 = u & 7;             // lane within 8-group
    const int b0 = t >> 6;            // softmax cell (b0, cs)
    const int cs = t & 63;

    // ---- pre-loop staging ----
    if (t < 512) {
        int il = t >> 6, b = (t >> 2) & 15, n0 = (t & 3) * 4;
        int i = blk + il * GBLK;
        *(float4*)&xb[il][b][n0] = *(const float4*)&x[((size_t)b * CI + i) * NI + n0];
    }
    float4 a4[8];
    if constexpr (MODE != 0) {
#pragma unroll
        for (int b = 0; b < 8; ++b)
            a4[b] = *(const float4*)&act_in[(size_t)(h * 8 + b) * KK + k4];
    }
    float lg[8];
    if constexpr (MODE == 2) {
#pragma unroll
        for (int il = 0; il < 8; ++il)
            lg[il] = logits[((size_t)b0 * CI + (blk + il * GBLK)) * CO + cs];
    }
    __syncthreads();

    float4 acc[8];
#pragma unroll
    for (int b = 0; b < 8; ++b) acc[b] = make_float4(0.f, 0.f, 0.f, 0.f);

    // stage one ni-half tile (8 rows = 64 KB) linearly: 4 x dwordx4 per thread.
    // LDS dest is lane-linear (byte 16*lane within each wave's 1 KB span).
    auto issue = [&](int hb) {
        int il = hb >> 1, p = hb & 1;
        const float* gb = w + ((size_t)(blk + il * GBLK) * NI + (size_t)p * 8) * KK + 4 * t;
        float* lb = wbuf[p] + 4 * t;
#pragma unroll
        for (int r = 0; r < 4; ++r)
            load_lds16(gb + 4096 * r, lb + 4096 * r);
    };

    auto compute_half = [&](int il, int p, float4(&dst)[8]) {
#pragma unroll
        for (int rg = 0; rg < 4; ++rg) {
            float4 wA = *(const float4*)&wbuf[p][(2 * rg) * KK + k4];
            float4 wB = *(const float4*)&wbuf[p][(2 * rg + 1) * KK + k4];
#pragma unroll
            for (int b = 0; b < 8; ++b) {
                float2 xv = *(const float2*)&xb[il][h * 8 + b][p * 8 + 2 * rg];
                dst[b].x = fmaf(xv.x, wA.x, dst[b].x);
                dst[b].y = fmaf(xv.x, wA.y, dst[b].y);
                dst[b].z = fmaf(xv.x, wA.z, dst[b].z);
                dst[b].w = fmaf(xv.x, wA.w, dst[b].w);
                dst[b].x = fmaf(xv.y, wB.x, dst[b].x);
                dst[b].y = fmaf(xv.y, wB.y, dst[b].y);
                dst[b].z = fmaf(xv.y, wB.z, dst[b].z);
                dst[b].w = fmaf(xv.y, wB.w, dst[b].w);
            }
        }
    };

    issue(0);
    issue(1);

#pragma unroll
    for (int il = 0; il < 8; ++il) {
        float4 v[8];
        if constexpr (MODE != 0) {
#pragma unroll
            for (int b = 0; b < 8; ++b) v[b] = make_float4(0.f, 0.f, 0.f, 0.f);
        }

        // ---- half 0 (ni 0..7) ----
        WAITVM4;                       // own loads of batch 2il arrived
        BAR();                         // => whole tile arrived (every wave waited)
        if constexpr (MODE == 0) compute_half(il, 0, acc);
        else                     compute_half(il, 0, v);
        WAITLGKM;                      // my reads of buf 0 retired
        BAR();                         // everyone's reads retired -> safe to overwrite
        if (il < 7) issue(2 * il + 2);

        // ---- half 1 (ni 8..15) ----
        if (il < 7) { WAITVM4; } else { WAITVM0; }
        BAR();
        if constexpr (MODE == 0) compute_half(il, 1, acc);
        else                     compute_half(il, 1, v);
        WAITLGKM;
        BAR();
        if (il < 7) issue(2 * il + 3);

        if constexpr (MODE != 0) {
            // ---- distances: per b, 8-lane reduce; static select (no dyn index) ----
            float dpv = 0.f;
#pragma unroll
            for (int b = 0; b < 8; ++b) {
                float d = v[b].x * a4[b].x + v[b].y * a4[b].y +
                          v[b].z * a4[b].z + v[b].w * a4[b].w;
#pragma unroll
                for (int m = 1; m < 8; m <<= 1)
                    d += __shfl_xor(d, m, 8);
                if (j8 == b) dpv = d;
            }
            sm[(h * 8 + j8) * 65 + co] = dpv;
            WAITLGKM;
            BAR();

            {   // ---- softmax over co: this thread owns cell (b0, cs) ----
                float l0 = sm[b0 * 65 + cs];
                if constexpr (MODE == 1) lg[il] = l0;     // store at end
                else                     l0 += lg[il];
                float mx = l0;
#pragma unroll
                for (int m = 1; m < 64; m <<= 1)
                    mx = fmaxf(mx, __shfl_xor(mx, m, 64));
                float e = __expf(l0 - mx);
                float s = e;
#pragma unroll
                for (int m = 1; m < 64; m <<= 1)
                    s += __shfl_xor(s, m, 64);
                sm[b0 * 65 + cs] = e / s;
            }
            WAITLGKM;
            BAR();

            // ---- routed accumulate ----
#pragma unroll
            for (int b = 0; b < 8; ++b) {
                float r = sm[(h * 8 + b) * 65 + co];
                acc[b].x = fmaf(r, v[b].x, acc[b].x);
                acc[b].y = fmaf(r, v[b].y, acc[b].y);
                acc[b].z = fmaf(r, v[b].z, acc[b].z);
                acc[b].w = fmaf(r, v[b].w, acc[b].w);
            }
            WAITLGKM;
            BAR();                     // sm reads done before next il writes
        }
    }

    // ---- epilogue (vmcnt drained by il=7 half 1) ----
#pragma unroll
    for (int b = 0; b < 8; ++b)
        *(float4*)&partials[((size_t)blk * BS + h * 8 + b) * KK + k4] = acc[b];

    if constexpr (MODE == 1) {
#pragma unroll
        for (int il = 0; il < 8; ++il)
            logits[((size_t)b0 * CI + (blk + il * GBLK)) * CO + cs] = lg[il];
    }
}

// 256 blocks x 128 threads; block owns 128 outputs; 4-way split over G + LDS combine
__global__ __launch_bounds__(128) void reduce_squash(
    const float* __restrict__ partials,
    const float* __restrict__ bias,
    float* __restrict__ act_out, float scale)
{
    __shared__ float4 sred[4][32];
    const int t = threadIdx.x;
    const int blk = blockIdx.x;
    const int lane = t & 31;
    const int gp = t >> 5;
    const int o4 = blk * 128 + lane * 4;
    const int b = o4 >> 11;
    const int kk = o4 & (KK - 1);
    const float* p = partials + (size_t)b * KK + kk;
    const size_t stride = (size_t)BS * KK;

    float4 s = make_float4(0.f, 0.f, 0.f, 0.f);
#pragma unroll 4
    for (int g = gp * 64; g < gp * 64 + 64; ++g) {
        float4 v = *(const float4*)(p + (size_t)g * stride);
        s.x += v.x; s.y += v.y; s.z += v.z; s.w += v.w;
    }
    sred[gp][lane] = s;
    __syncthreads();

    if (t < 32) {
        float4 v0 = sred[0][t], v1 = sred[1][t], v2 = sred[2][t], v3 = sred[3][t];
        float4 v;
        v.x = (v0.x + v1.x) + (v2.x + v3.x);
        v.y = (v0.y + v1.y) + (v2.y + v3.y);
        v.z = (v0.z + v1.z) + (v2.z + v3.z);
        v.w = (v0.w + v1.w) + (v2.w + v3.w);
        const int ot = blk * 128 + t * 4;
        float4 bb = *(const float4*)&bias[ot & (KK - 1)];
        v.x = v.x * scale + bb.x;
        v.y = v.y * scale + bb.y;
        v.z = v.z * scale + bb.z;
        v.w = v.w * scale + bb.w;
        float n2 = v.x * v.x + v.y * v.y + v.z * v.z + v.w * v.w;
#pragma unroll
        for (int m = 1; m < 8; m <<= 1) n2 += __shfl_xor(n2, m, 8);
        float norm = sqrtf(n2);
        float sc = norm / (1.f + n2);
        float4 o = make_float4(v.x * sc, v.y * sc, v.z * sc, v.w * sc);
        *(float4*)&act_out[ot] = o;
    }
}

extern "C" void kernel_launch(void* const* d_in, const int* in_sizes, int n_in,
                              void* d_out, int out_size, void* d_ws, size_t ws_size,
                              hipStream_t stream) {
    const float* x = (const float*)d_in[0];
    const float* w = (const float*)d_in[1];
    const float* bias = (const float*)d_in[2];
    float* out = (float*)d_out;

    char* p = (char*)d_ws;
    float* partials = (float*)p; p += (size_t)GBLK * BS * KK * 4;  // 33.5 MB
    float* logits = (float*)p;   p += (size_t)BS * CI * CO * 4;    // 8 MB
    float* act1 = (float*)p;     p += (size_t)BS * KK * 4;
    float* act2 = (float*)p;

    dim3 blk(1024), grid(GBLK);
    pass_kernel<0><<<grid, blk, 0, stream>>>(x, w, nullptr, logits, partials);
    reduce_squash<<<256, 128, 0, stream>>>(partials, bias, act1, 1.0f / (float)CO);
    pass_kernel<1><<<grid, blk, 0, stream>>>(x, w, act1, logits, partials);
    reduce_squash<<<256, 128, 0, stream>>>(partials, bias, act2, 1.0f);
    pass_kernel<2><<<grid, blk, 0, stream>>>(x, w, act2, logits, partials);
    reduce_squash<<<256, 128, 0, stream>>>(partials, bias, out, 1.0f);
}